// Round 10
// baseline (108.884 us; speedup 1.0000x reference)
//
#include <hip/hip_runtime.h>

// ---------------- problem constants ----------------
#define N1 27648            // 96*96*3
#define N2 6912             // 48*48*3
#define N3 1728             // 24*24*3
#define NTOT 36288          // N1+N2+N3
#define BATCH_ 16
#define C_ 3
#define GRP (BATCH_ * C_)   // 48
#define MROWS (NTOT * C_)   // 108864
#define TOPK 500
#define NBINS 2304          // (0x3F800000 - 0x3D400000) >> 14, covers s in (0.046, 1)
#define CCAP 2048
#define BASEBITS 0x3D400000u
#define TPRE 0.5f           // prefilter threshold; 500th score ~0.67 on this data
#define BLKX 142            // ceil(NTOT/256) decode blocks per batch
#define SEGCAP 96           // max staged candidates per (block,class); ~20 expected

// ---- workspace layout (split path; no atomics, no zeroing needed) ----
#define OFF_CNT    0ull
#define SZ_CNT     32768ull                              // GRP*BLKX u32 = 27.3KB, padded
#define OFF_SEG    (OFF_CNT + SZ_CNT)
#define SZ_SEG     ((size_t)GRP * BLKX * SEGCAP * 8)     // 5.23 MB
#define OFF_KEYS   (OFF_SEG + SZ_SEG)
#define SZ_KEYS    ((size_t)GRP * 512 * 8)               // 192 KB
#define OFF_BOXES  (OFF_KEYS + SZ_KEYS)
#define SZ_BOXES   ((size_t)GRP * 512 * 16)              // 384 KB
#define OFF_MASKS  (OFF_BOXES + SZ_BOXES)
#define SZ_MASKS   ((size_t)GRP * 4096 * 8)              // 1.5 MB ([w][512] per group)
#define OFF_KCNT   (OFF_MASKS + SZ_MASKS)
#define SZ_KCNT    4096ull
#define WS_NEED    (OFF_KCNT + SZ_KCNT)                  // ~7.4 MB

__device__ __forceinline__ float sigm(float x) { return 1.0f / (1.0f + expf(-x)); }

// score for candidate (b, n, c); identical float op sequence everywhere it is used
__device__ __forceinline__ float score_of(int b, int n, int c,
    const float* __restrict__ o1, const float* __restrict__ o2, const float* __restrict__ o3)
{
    const float* o; int ln, Ns;
    if (n < N1)           { o = o1; ln = n;             Ns = N1; }
    else if (n < N1 + N2) { o = o2; ln = n - N1;        Ns = N2; }
    else                  { o = o3; ln = n - (N1 + N2); Ns = N3; }
    const float* r = o + ((size_t)b * Ns + ln) * 8;
    return sigm(r[4]) * sigm(r[5 + c]);
}

// wave-aggregated LDS-counter push: one atomic per wave per iteration
__device__ __forceinline__ unsigned wave_push(bool pred, unsigned* cntp)
{
    unsigned long long mb = __ballot(pred);
    unsigned pos = 0xFFFFFFFFu;
    if (pred) {
        int lane = threadIdx.x & 63;
        int leader = __ffsll((long long)mb) - 1;
        unsigned total = (unsigned)__popcll(mb);
        unsigned base = 0;
        if (lane == leader) base = atomicAdd(cntp, total);
        base = __shfl(base, leader);
        pos = base + (unsigned)__popcll(mb & ((1ull << lane) - 1ull));
    }
    return pos;
}

// wave-0 suffix scan of hist -> threshold bin of the TOPK-th score + total count
__device__ __forceinline__ void scan_tb(const unsigned* hist,
                                        unsigned* sh_tb, unsigned* sh_tot)
{
    const int tid = threadIdx.x;
    if (tid < 64) {
        const int CHUNK = NBINS / 64;                    // 36
        int base_i = tid * CHUNK;
        unsigned own = 0;
        #pragma unroll
        for (int k = 0; k < CHUNK; ++k) own += hist[base_i + k];
        unsigned sfx = own;
        #pragma unroll
        for (int off = 1; off < 64; off <<= 1) {
            unsigned v = __shfl_down(sfx, off, 64);
            sfx += (tid + off < 64) ? v : 0u;
        }
        unsigned sfxn = sfx - own;                       // suffix starting at next chunk
        if (tid == 0) { *sh_tot = sfx; if (sfx < TOPK) *sh_tb = 0u; }
        if (sfx >= TOPK && sfxn < TOPK) {                // unique crossing lane
            unsigned cum = sfxn, tb = (unsigned)base_i;
            for (int k = CHUNK - 1; k >= 0; --k) {
                cum += hist[base_i + k];
                if (cum >= TOPK) { tb = (unsigned)(base_i + k); break; }
            }
            *sh_tb = tb;
        }
    }
}

// ---------------- kernel 1: decode + defaults + segment prefilter (no atomics) --------
// grid (BLKX, BATCH_); b = blockIdx.y is block-uniform
__global__ __launch_bounds__(256) void decode_filter_kernel(
    const float* __restrict__ o1, const float* __restrict__ o2, const float* __restrict__ o3,
    const float* __restrict__ a1, const float* __restrict__ a2, const float* __restrict__ a3,
    const float* __restrict__ f1, const float* __restrict__ f2, const float* __restrict__ f3,
    const float* __restrict__ s1, const float* __restrict__ s2, const float* __restrict__ s3,
    float* __restrict__ out,
    unsigned* __restrict__ cntArr, unsigned long long* __restrict__ seg)
{
    __shared__ unsigned lcnt[C_];
    __shared__ unsigned long long stage[C_][256];

    const int tid = threadIdx.x;
    const int x = blockIdx.x;
    const int n = x * 256 + tid;
    const int b = blockIdx.y;

    if (tid < C_) lcnt[tid] = 0u;
    __syncthreads();

    if (n < NTOT) {
        const float *o, *anc, *off, *st; int ln, Ns;
        if (n < N1)           { o = o1; anc = a1; off = f1; st = s1; ln = n;             Ns = N1; }
        else if (n < N1 + N2) { o = o2; anc = a2; off = f2; st = s2; ln = n - N1;        Ns = N2; }
        else                  { o = o3; anc = a3; off = f3; st = s3; ln = n - (N1 + N2); Ns = N3; }
        const float* r = o + ((size_t)b * Ns + ln) * 8;
        float4 v0 = *(const float4*)r;        // xy, wh
        float4 v1 = *(const float4*)(r + 4);  // obj, cls0..2

        // decode box (same op sequence as reference)
        float sx = sigm(v0.x);
        float sy = sigm(v0.y);
        float cx = (sx + off[2 * ln + 0]) * st[0];
        float cy = (sy + off[2 * ln + 1]) * st[1];
        float hx = 0.5f * expf(v0.z) * anc[2 * ln + 0];
        float hy = 0.5f * expf(v0.w) * anc[2 * ln + 1];
        float4 bb = make_float4(cx - hx, cy - hy, cx + hx, cy + hy);

        size_t base = (size_t)b * MROWS + (size_t)n * C_;
        float* ids = out;
        float* scs = out + (size_t)BATCH_ * MROWS;
        float* bbs = out + 2ull * BATCH_ * MROWS;

        // -1 defaults (never re-read on device -> NT); bbs re-read by topk -> normal
        __builtin_nontemporal_store(-1.0f, &ids[base + 0]);
        __builtin_nontemporal_store(-1.0f, &ids[base + 1]);
        __builtin_nontemporal_store(-1.0f, &ids[base + 2]);
        __builtin_nontemporal_store(-1.0f, &scs[base + 0]);
        __builtin_nontemporal_store(-1.0f, &scs[base + 1]);
        __builtin_nontemporal_store(-1.0f, &scs[base + 2]);
        float4* bp = (float4*)(bbs + base * 4);
        bp[0] = bb; bp[1] = bb; bp[2] = bb;

        // prefilter into LDS staging (LDS atomics only; ~20 positives per block/class)
        if (cntArr != nullptr) {
            float sobj = sigm(v1.x);
            float s[3] = { sobj * sigm(v1.y), sobj * sigm(v1.z), sobj * sigm(v1.w) };
            #pragma unroll
            for (int c = 0; c < C_; ++c) {
                if (s[c] > TPRE) {
                    unsigned p = atomicAdd(&lcnt[c], 1u);
                    stage[c][p] =
                        ((unsigned long long)__float_as_uint(s[c]) << 32) | (unsigned)(~n);
                }
            }
        }
    }

    if (cntArr != nullptr) {
        __syncthreads();
        // deterministic per-(block,class) segment; count written unconditionally
        if (tid < C_)
            cntArr[(b * C_ + tid) * BLKX + x] = lcnt[tid];
        #pragma unroll
        for (int c = 0; c < C_; ++c) {
            unsigned m = lcnt[c];
            if (m > SEGCAP) m = SEGCAP;
            if ((unsigned)tid < m)
                seg[((size_t)(b * C_ + c) * BLKX + x) * SEGCAP + tid] = stage[c][tid];
        }
    }
}

// ---------------- kernel 2: per-(b,c) exact top-500, sorted -> ws ----------------
__global__ __launch_bounds__(512) void topk_kernel(
    const float* __restrict__ o1, const float* __restrict__ o2, const float* __restrict__ o3,
    const float* __restrict__ out,
    const unsigned* __restrict__ cntArr, const unsigned long long* __restrict__ seg,
    unsigned long long* __restrict__ gkeys, float4* __restrict__ gboxes,
    unsigned* __restrict__ kcnt)
{
    const int g = blockIdx.x;
    const int b = g / C_;
    const int c = g - b * C_;
    const int tid = threadIdx.x;

    __shared__ unsigned long long keys[CCAP];     // 16 KB
    __shared__ unsigned int hist[NBINS];          // 9 KB
    __shared__ unsigned int sh_tb, sh_tot, sh_cnt, sh_flag;

    const unsigned* CNT = cntArr + g * BLKX;
    const unsigned long long* SEG = seg + (size_t)g * BLKX * SEGCAP;

    // ---- phase 0: overflow check (any block exceeded SEGCAP -> raw rescan) ----
    if (tid == 0) { sh_cnt = 0u; sh_flag = 0u; }
    for (int i = tid; i < NBINS; i += 512) hist[i] = 0u;
    __syncthreads();
    {
        unsigned ovf = 0;
        for (int x = tid; x < BLKX; x += 512)
            if (CNT[x] > SEGCAP) ovf = 1;
        if (ovf) atomicOr(&sh_flag, 1u);
    }
    __syncthreads();
    bool useRaw = (sh_flag != 0u);

    // ---- phase 1: histogram ----
    if (!useRaw) {
        for (int t = tid; t < BLKX * SEGCAP; t += 512) {
            int x = t / SEGCAP, slot = t - x * SEGCAP;
            if (slot < (int)CNT[x]) {
                unsigned bin = ((unsigned)(SEG[t] >> 32) - BASEBITS) >> 14;
                if (bin > NBINS - 1u) bin = NBINS - 1u;
                atomicAdd(&hist[bin], 1u);
            }
        }
        __syncthreads();
        scan_tb(hist, &sh_tb, &sh_tot);
        __syncthreads();
        if (sh_tot < TOPK) useRaw = true;        // prefilter missed the tail -> rescan
    }
    if (useRaw) {
        for (int i = tid; i < NBINS; i += 512) hist[i] = 0u;
        __syncthreads();
        for (int n = tid; n < NTOT; n += 512) {
            float s = score_of(b, n, c, o1, o2, o3);
            if (s > 0.05f) {
                unsigned bin = (__float_as_uint(s) - BASEBITS) >> 14;
                if (bin > NBINS - 1u) bin = NBINS - 1u;
                atomicAdd(&hist[bin], 1u);
            }
        }
        __syncthreads();
        scan_tb(hist, &sh_tb, &sh_tot);
        __syncthreads();
    }

    // ---- phase 3: collect candidates with bin >= tb (wave-aggregated push) ----
    const unsigned tb = sh_tb;
    if (!useRaw) {
        const int nIter = (BLKX * SEGCAP + 511) & ~511;
        for (int t = tid; t < nIter; t += 512) {
            bool pred = false; unsigned long long key = 0ull;
            if (t < BLKX * SEGCAP) {
                int x = t / SEGCAP, slot = t - x * SEGCAP;
                if (slot < (int)CNT[x]) {
                    key = SEG[t];
                    unsigned bin = ((unsigned)(key >> 32) - BASEBITS) >> 14;
                    if (bin > NBINS - 1u) bin = NBINS - 1u;
                    pred = (bin >= tb);
                }
            }
            unsigned p = wave_push(pred, &sh_cnt);
            if (pred && p < CCAP) keys[p] = key;
        }
    } else {
        const int nIter = (NTOT + 511) & ~511;
        for (int n = tid; n < nIter; n += 512) {
            bool pred = false; unsigned long long key = 0ull;
            if (n < NTOT) {
                float s = score_of(b, n, c, o1, o2, o3);
                if (s > 0.05f) {
                    unsigned bits = __float_as_uint(s);
                    unsigned bin = (bits - BASEBITS) >> 14;
                    if (bin > NBINS - 1u) bin = NBINS - 1u;
                    if (bin >= tb) {
                        pred = true;
                        key = ((unsigned long long)bits << 32) | (unsigned)(~n);
                    }
                }
            }
            unsigned p = wave_push(pred, &sh_cnt);
            if (pred && p < CCAP) keys[p] = key;
        }
    }
    __syncthreads();

    const unsigned cnt2 = min(sh_cnt, (unsigned)CCAP);
    unsigned S2 = 2;
    while (S2 < cnt2) S2 <<= 1;                          // next pow2 (typically 512)
    for (unsigned i = tid; i < S2; i += 512)
        if (i >= cnt2) keys[i] = 0ull;                   // pad sorts last (desc)
    __syncthreads();

    // ---- phase 4: bitonic sort, descending (score desc, index asc) ----
    for (unsigned k = 2; k <= S2; k <<= 1) {
        for (unsigned j = k >> 1; j > 0; j >>= 1) {
            for (unsigned i = tid; i < S2; i += 512) {
                unsigned ixj = i ^ j;
                if (ixj > i) {
                    unsigned long long x = keys[i], y = keys[ixj];
                    bool desc = ((i & k) == 0);
                    if (desc ? (x < y) : (x > y)) { keys[i] = y; keys[ixj] = x; }
                }
            }
            __syncthreads();
        }
    }

    const int K = (int)min(cnt2, (unsigned)TOPK);

    // ---- phase 5: emit sorted keys + gathered boxes to ws ----
    if (tid == 0) kcnt[g] = (unsigned)K;
    if (tid < K) {
        unsigned long long key = keys[tid];
        gkeys[(size_t)g * 512 + tid] = key;
        unsigned idx = ~(unsigned)(key & 0xFFFFFFFFull);
        const float* bbs = out + 2ull * BATCH_ * MROWS;
        gboxes[(size_t)g * 512 + tid] =
            *(const float4*)(bbs + ((size_t)b * MROWS + (size_t)idx * C_) * 4);
    }
}

// ---------------- kernel 3: mask word-columns; block = (group, word) ----------------
__global__ __launch_bounds__(256) void masks_kernel(
    const float4* __restrict__ gboxes, const unsigned* __restrict__ kcnt,
    unsigned long long* __restrict__ gmasks)
{
    const int g = blockIdx.x;
    const int w = blockIdx.y;
    const int K = (int)kcnt[g];

    __shared__ float bx[TOPK * 4];   // 8 KB
    __shared__ float ar[TOPK];       // 2 KB

    const float4* B = gboxes + (size_t)g * 512;
    for (int j = threadIdx.x; j < K; j += 256) {
        float4 v = B[j];
        bx[j*4+0] = v.x; bx[j*4+1] = v.y; bx[j*4+2] = v.z; bx[j*4+3] = v.w;
        ar[j] = fmaxf(v.z - v.x, 0.0f) * fmaxf(v.w - v.y, 0.0f);
    }
    __syncthreads();

    unsigned long long* M = gmasks + (size_t)g * 4096 + (size_t)w * 512;
    const int j0 = w * 64;
    const int jhi = (K < j0 + 64) ? K : j0 + 64;

    for (int i = threadIdx.x; i < K; i += 256) {
        unsigned long long word = 0ull;
        if (i + 1 < jhi) {
            float xi1 = bx[i*4+0], yi1 = bx[i*4+1], xi2 = bx[i*4+2], yi2 = bx[i*4+3];
            float ai = ar[i];
            // wave-uniform j (broadcast LDS reads); j>i folded into bit test
            for (int j = j0; j < jhi; ++j) {
                float xj1 = bx[j*4+0], yj1 = bx[j*4+1], xj2 = bx[j*4+2], yj2 = bx[j*4+3];
                float aj = ar[j];
                float iw = fmaxf(fminf(xi2, xj2) - fmaxf(xi1, xj1), 0.0f);
                float ih = fmaxf(fminf(yi2, yj2) - fmaxf(yi1, yj1), 0.0f);
                float inter = iw * ih;
                float iou = inter / (ai + aj - inter + 1e-12f);
                if (iou > 0.5f && j > i) word |= 1ull << (j - j0);
            }
        }
        M[i] = word;
    }
}

// ---------------- kernel 4: greedy scan + scatter; block = group ----------------
// Named scalar registers (no arrays -> no spill/remat), branchless vote body.
__global__ __launch_bounds__(512) void greedy_kernel(
    const unsigned long long* __restrict__ gmasks,
    const unsigned long long* __restrict__ gkeys,
    const unsigned* __restrict__ kcnt, float* __restrict__ out)
{
    const int g = blockIdx.x;
    const int b = g / C_;
    const int c = g - b * C_;
    const int tid = threadIdx.x;
    const int K = (int)kcnt[g];

    __shared__ unsigned long long mlds[512 * 9];        // row pad 8->9: conflict-free
    __shared__ unsigned long long keep_s[8];

    // preload masks: coalesced over i for each word w; rows >= K zeroed
    const unsigned long long* GM = gmasks + (size_t)g * 4096;
    for (int t = tid; t < 8 * 512; t += 512) {
        int w = t >> 9, i = t & 511;
        mlds[i * 9 + w] = (i < K) ? GM[w * 512 + i] : 0ull;
    }
    __syncthreads();

    if (tid < 64) {
        const int lane8 = tid & 7;                      // all lanes read word lane8 (broadcast)
        unsigned long long removed = 0ull, keep = 0ull;
        const int Kpad = (K + 7) & ~7;

        unsigned long long m0 = mlds[0*9+lane8], m1 = mlds[1*9+lane8],
                           m2 = mlds[2*9+lane8], m3 = mlds[3*9+lane8],
                           m4 = mlds[4*9+lane8], m5 = mlds[5*9+lane8],
                           m6 = mlds[6*9+lane8], m7 = mlds[7*9+lane8];

        for (int i0 = 0; i0 < Kpad; i0 += 8) {
            int nb = (i0 + 8 < 512) ? (i0 + 8) : 0;     // wrap-safe; values unused at end
            unsigned long long n0 = mlds[(nb+0)*9+lane8], n1 = mlds[(nb+1)*9+lane8],
                               n2 = mlds[(nb+2)*9+lane8], n3 = mlds[(nb+3)*9+lane8],
                               n4 = mlds[(nb+4)*9+lane8], n5 = mlds[(nb+5)*9+lane8],
                               n6 = mlds[(nb+6)*9+lane8], n7 = mlds[(nb+7)*9+lane8];

            #define GSTEP(t, mt) { \
                int i = i0 + t; \
                int w = i >> 6, bp = i & 63; \
                bool mine = (tid == w) && ((removed >> bp) & 1ull); \
                unsigned long long alive = __any(mine) ? 0ull : ~0ull; \
                keep |= ((tid == w) ? (1ull << bp) : 0ull) & alive; \
                removed |= mt & alive; \
            }
            GSTEP(0, m0) GSTEP(1, m1) GSTEP(2, m2) GSTEP(3, m3)
            GSTEP(4, m4) GSTEP(5, m5) GSTEP(6, m6) GSTEP(7, m7)
            #undef GSTEP

            m0=n0; m1=n1; m2=n2; m3=n3; m4=n4; m5=n5; m6=n6; m7=n7;
        }
        if (tid < 8) keep_s[tid] = keep;
    }
    __syncthreads();

    const unsigned long long* GK = gkeys + (size_t)g * 512;
    for (int i = tid; i < K; i += 512) {
        if ((keep_s[i >> 6] >> (i & 63)) & 1ull) {
            unsigned long long key = GK[i];
            unsigned idx = ~(unsigned)(key & 0xFFFFFFFFull);
            float sc = __uint_as_float((unsigned)(key >> 32));
            size_t row = (size_t)b * MROWS + (size_t)idx * C_ + c;
            out[row] = (float)c;                               // id
            out[(size_t)BATCH_ * MROWS + row] = sc;            // score
        }
    }
}

// ---------------- monolithic fallback (small ws; full in-kernel rescan) ----------------
__global__ __launch_bounds__(512) void select_nms_mono(
    const float* __restrict__ o1, const float* __restrict__ o2, const float* __restrict__ o3,
    float* __restrict__ out)
{
    const int g = blockIdx.x;
    const int b = g / C_;
    const int c = g - b * C_;
    const int tid = threadIdx.x;

    __shared__ unsigned long long smem[7048];
    __shared__ unsigned int sh_tb, sh_tot, sh_cnt;
    __shared__ unsigned long long keepw[8];

    unsigned long long* keys = smem;
    unsigned int* hist = (unsigned int*)(smem + CCAP);
    float* boxes = (float*)(smem + CCAP);
    unsigned long long* masks = smem + 3048;

    for (int i = tid; i < NBINS; i += 512) hist[i] = 0u;
    if (tid == 0) sh_cnt = 0u;
    __syncthreads();

    for (int n = tid; n < NTOT; n += 512) {
        float s = score_of(b, n, c, o1, o2, o3);
        if (s > 0.05f) {
            unsigned bin = (__float_as_uint(s) - BASEBITS) >> 14;
            if (bin > NBINS - 1u) bin = NBINS - 1u;
            atomicAdd(&hist[bin], 1u);
        }
    }
    __syncthreads();
    scan_tb(hist, &sh_tb, &sh_tot);
    __syncthreads();

    const unsigned tb = sh_tb;
    for (int n = tid; n < NTOT; n += 512) {
        float s = score_of(b, n, c, o1, o2, o3);
        if (s > 0.05f) {
            unsigned bits = __float_as_uint(s);
            unsigned bin = (bits - BASEBITS) >> 14;
            if (bin > NBINS - 1u) bin = NBINS - 1u;
            if (bin >= tb) {
                unsigned p = atomicAdd(&sh_cnt, 1u);
                if (p < CCAP)
                    keys[p] = ((unsigned long long)bits << 32) | (unsigned)(~n);
            }
        }
    }
    __syncthreads();

    const unsigned cnt2 = min(sh_cnt, (unsigned)CCAP);
    unsigned S2 = 2;
    while (S2 < cnt2) S2 <<= 1;
    for (unsigned i = tid; i < S2; i += 512)
        if (i >= cnt2) keys[i] = 0ull;
    __syncthreads();

    for (unsigned k = 2; k <= S2; k <<= 1) {
        for (unsigned j = k >> 1; j > 0; j >>= 1) {
            for (unsigned i = tid; i < S2; i += 512) {
                unsigned ixj = i ^ j;
                if (ixj > i) {
                    unsigned long long x = keys[i], y = keys[ixj];
                    bool desc = ((i & k) == 0);
                    if (desc ? (x < y) : (x > y)) { keys[i] = y; keys[ixj] = x; }
                }
            }
            __syncthreads();
        }
    }

    const int K = (int)min(cnt2, (unsigned)TOPK);

    {
        const float* bbs = out + 2ull * BATCH_ * MROWS;
        if (tid < K) {
            unsigned idx = ~(unsigned)(keys[tid] & 0xFFFFFFFFull);
            float4 bb = *(const float4*)(bbs + ((size_t)b * MROWS + (size_t)idx * C_) * 4);
            ((float4*)boxes)[tid] = bb;
        }
    }
    __syncthreads();

    {
        const int nw = (K + 63) >> 6;
        for (int t = tid; t < K * nw; t += 512) {
            int w = t / K;
            int i = t - w * K;
            float xi1 = boxes[i*4+0], yi1 = boxes[i*4+1], xi2 = boxes[i*4+2], yi2 = boxes[i*4+3];
            float ai = fmaxf(xi2 - xi1, 0.0f) * fmaxf(yi2 - yi1, 0.0f);
            unsigned long long word = 0ull;
            int jlo = (i + 1 > w * 64) ? i + 1 : w * 64;
            int jhi = (K < (w + 1) * 64) ? K : (w + 1) * 64;
            for (int j = jlo; j < jhi; ++j) {
                float xj1 = boxes[j*4+0], yj1 = boxes[j*4+1], xj2 = boxes[j*4+2], yj2 = boxes[j*4+3];
                float aj = fmaxf(xj2 - xj1, 0.0f) * fmaxf(yj2 - yj1, 0.0f);
                float iw = fmaxf(fminf(xi2, xj2) - fmaxf(xi1, xj1), 0.0f);
                float ih = fmaxf(fminf(yi2, yj2) - fmaxf(yi1, yj1), 0.0f);
                float inter = iw * ih;
                float iou = inter / (ai + aj - inter + 1e-12f);
                if (iou > 0.5f) word |= 1ull << (j & 63);
            }
            masks[i * 8 + w] = word;
        }
    }
    __syncthreads();

    if (tid < 64) {
        unsigned long long removed = 0ull, keep = 0ull;
        for (int i = 0; i < K; ++i) {
            unsigned long long mw = (tid < 8) ? masks[i * 8 + tid] : 0ull;
            int w = i >> 6, bp = i & 63;
            bool mine = (tid == w) && ((removed >> bp) & 1ull);
            if (!__any(mine)) {
                if (tid == w) keep |= 1ull << bp;
                removed |= mw;
            }
        }
        if (tid < 8) keepw[tid] = keep;
    }
    __syncthreads();

    if (tid < K && ((keepw[tid >> 6] >> (tid & 63)) & 1ull)) {
        unsigned long long key = keys[tid];
        unsigned idx = ~(unsigned)(key & 0xFFFFFFFFull);
        float sc = __uint_as_float((unsigned)(key >> 32));
        size_t row = (size_t)b * MROWS + (size_t)idx * C_ + c;
        out[row] = (float)c;
        out[(size_t)BATCH_ * MROWS + row] = sc;
    }
}

extern "C" void kernel_launch(void* const* d_in, const int* in_sizes, int n_in,
                              void* d_out, int out_size, void* d_ws, size_t ws_size,
                              hipStream_t stream)
{
    const float* o1 = (const float*)d_in[0];
    const float* o2 = (const float*)d_in[1];
    const float* o3 = (const float*)d_in[2];
    const float* a1 = (const float*)d_in[3];
    const float* a2 = (const float*)d_in[4];
    const float* a3 = (const float*)d_in[5];
    const float* f1 = (const float*)d_in[6];
    const float* f2 = (const float*)d_in[7];
    const float* f3 = (const float*)d_in[8];
    const float* s1 = (const float*)d_in[9];
    const float* s2 = (const float*)d_in[10];
    const float* s3 = (const float*)d_in[11];
    float* out = (float*)d_out;

    if (ws_size >= WS_NEED) {
        unsigned*           cntArr = (unsigned*)((char*)d_ws + OFF_CNT);
        unsigned long long* seg    = (unsigned long long*)((char*)d_ws + OFF_SEG);
        unsigned long long* gkeys  = (unsigned long long*)((char*)d_ws + OFF_KEYS);
        float4*             gboxes = (float4*)((char*)d_ws + OFF_BOXES);
        unsigned long long* gmasks = (unsigned long long*)((char*)d_ws + OFF_MASKS);
        unsigned*           kcnt   = (unsigned*)((char*)d_ws + OFF_KCNT);

        decode_filter_kernel<<<dim3(BLKX, BATCH_), dim3(256), 0, stream>>>(
            o1, o2, o3, a1, a2, a3, f1, f2, f3, s1, s2, s3, out, cntArr, seg);
        topk_kernel<<<dim3(GRP), dim3(512), 0, stream>>>(
            o1, o2, o3, out, cntArr, seg, gkeys, gboxes, kcnt);
        masks_kernel<<<dim3(GRP, 8), dim3(256), 0, stream>>>(gboxes, kcnt, gmasks);
        greedy_kernel<<<dim3(GRP), dim3(512), 0, stream>>>(gmasks, gkeys, kcnt, out);
    } else {
        decode_filter_kernel<<<dim3(BLKX, BATCH_), dim3(256), 0, stream>>>(
            o1, o2, o3, a1, a2, a3, f1, f2, f3, s1, s2, s3, out, nullptr, nullptr);
        select_nms_mono<<<dim3(GRP), dim3(512), 0, stream>>>(o1, o2, o3, out);
    }
}

// Round 11
// 94.202 us; speedup vs baseline: 1.1559x; 1.1559x over previous
//
#include <hip/hip_runtime.h>

// ---------------- problem constants ----------------
#define N1 27648            // 96*96*3
#define N2 6912             // 48*48*3
#define N3 1728             // 24*24*3
#define NTOT 36288          // N1+N2+N3
#define BATCH_ 16
#define C_ 3
#define GRP (BATCH_ * C_)   // 48
#define MROWS (NTOT * C_)   // 108864
#define TOPK 500
#define NBINS 2304          // (0x3F800000 - 0x3D400000) >> 14, covers s in (0.046, 1)
#define CCAP 2048
#define BASEBITS 0x3D400000u
#define TPRE 0.5f           // prefilter threshold; 500th score ~0.67 on this data
#define LISTCAP 4096        // per-(b,c) list capacity (expected cnt ~2800)
#define CNT_STRIDE 32       // u32 units -> each global counter on its own 128B line

// ---- workspace layout (split path) ----
#define OFF_LIST   8192ull
#define SZ_LIST    ((size_t)GRP * LISTCAP * 8)          // 1.50 MB
#define OFF_KEYS   (OFF_LIST + SZ_LIST)
#define SZ_KEYS    ((size_t)GRP * 512 * 8)              // 192 KB
#define OFF_BOXES  (OFF_KEYS + SZ_KEYS)
#define SZ_BOXES   ((size_t)GRP * 512 * 16)             // 384 KB
#define OFF_MASKS  (OFF_BOXES + SZ_BOXES)
#define SZ_MASKS   ((size_t)GRP * 4096 * 8)             // 1.5 MB ([w][512] per group)
#define OFF_KCNT   (OFF_MASKS + SZ_MASKS)
#define SZ_KCNT    4096ull
#define WS_NEED    (OFF_KCNT + SZ_KCNT)                 // ~3.77 MB

__device__ __forceinline__ float sigm(float x) { return 1.0f / (1.0f + expf(-x)); }

// score for candidate (b, n, c); identical float op sequence everywhere it is used
__device__ __forceinline__ float score_of(int b, int n, int c,
    const float* __restrict__ o1, const float* __restrict__ o2, const float* __restrict__ o3)
{
    const float* o; int ln, Ns;
    if (n < N1)           { o = o1; ln = n;             Ns = N1; }
    else if (n < N1 + N2) { o = o2; ln = n - N1;        Ns = N2; }
    else                  { o = o3; ln = n - (N1 + N2); Ns = N3; }
    const float* r = o + ((size_t)b * Ns + ln) * 8;
    return sigm(r[4]) * sigm(r[5 + c]);
}

// wave-aggregated LDS-counter push: one atomic per wave per iteration
__device__ __forceinline__ unsigned wave_push(bool pred, unsigned* cntp)
{
    unsigned long long mb = __ballot(pred);
    unsigned pos = 0xFFFFFFFFu;
    if (pred) {
        int lane = threadIdx.x & 63;
        int leader = __ffsll((long long)mb) - 1;
        unsigned total = (unsigned)__popcll(mb);
        unsigned base = 0;
        if (lane == leader) base = atomicAdd(cntp, total);
        base = __shfl(base, leader);
        pos = base + (unsigned)__popcll(mb & ((1ull << lane) - 1ull));
    }
    return pos;
}

// wave-0 suffix scan of hist -> threshold bin of the TOPK-th score
__device__ __forceinline__ void scan_tb(const unsigned* hist, unsigned* sh_tb)
{
    const int tid = threadIdx.x;
    if (tid < 64) {
        const int CHUNK = NBINS / 64;                    // 36
        int base_i = tid * CHUNK;
        unsigned own = 0;
        #pragma unroll
        for (int k = 0; k < CHUNK; ++k) own += hist[base_i + k];
        unsigned sfx = own;
        #pragma unroll
        for (int off = 1; off < 64; off <<= 1) {
            unsigned v = __shfl_down(sfx, off, 64);
            sfx += (tid + off < 64) ? v : 0u;
        }
        unsigned sfxn = sfx - own;                       // suffix starting at next chunk
        if (tid == 0 && sfx < TOPK) *sh_tb = 0u;         // fewer than 500 total
        if (sfx >= TOPK && sfxn < TOPK) {                // unique crossing lane
            unsigned cum = sfxn, tb = (unsigned)base_i;
            for (int k = CHUNK - 1; k >= 0; --k) {
                cum += hist[base_i + k];
                if (cum >= TOPK) { tb = (unsigned)(base_i + k); break; }
            }
            *sh_tb = tb;
        }
    }
}

// ---------------- kernel 0: zero the 48 per-group counters ----------------
__global__ __launch_bounds__(64) void zerocnt_kernel(unsigned* __restrict__ cnts)
{
    if (threadIdx.x < GRP) cnts[threadIdx.x * CNT_STRIDE] = 0u;
}

// ---------------- kernel 1: decode + defaults + block-aggregated prefilter ----------------
// grid (ceil(NTOT/256), BATCH_); b = blockIdx.y is block-uniform
__global__ __launch_bounds__(256) void decode_filter_kernel(
    const float* __restrict__ o1, const float* __restrict__ o2, const float* __restrict__ o3,
    const float* __restrict__ a1, const float* __restrict__ a2, const float* __restrict__ a3,
    const float* __restrict__ f1, const float* __restrict__ f2, const float* __restrict__ f3,
    const float* __restrict__ s1, const float* __restrict__ s2, const float* __restrict__ s3,
    float* __restrict__ out,
    unsigned* __restrict__ cnts, unsigned long long* __restrict__ list, int listcap)
{
    __shared__ unsigned lcnt[C_];
    __shared__ unsigned lbase[C_];
    __shared__ unsigned long long stage[C_][256];

    const int tid = threadIdx.x;
    const int n = blockIdx.x * 256 + tid;
    const int b = blockIdx.y;

    if (tid < C_) lcnt[tid] = 0u;
    __syncthreads();

    if (n < NTOT) {
        const float *o, *anc, *off, *st; int ln, Ns;
        if (n < N1)           { o = o1; anc = a1; off = f1; st = s1; ln = n;             Ns = N1; }
        else if (n < N1 + N2) { o = o2; anc = a2; off = f2; st = s2; ln = n - N1;        Ns = N2; }
        else                  { o = o3; anc = a3; off = f3; st = s3; ln = n - (N1 + N2); Ns = N3; }
        const float* r = o + ((size_t)b * Ns + ln) * 8;
        float4 v0 = *(const float4*)r;        // xy, wh
        float4 v1 = *(const float4*)(r + 4);  // obj, cls0..2

        // decode box (same op sequence as reference)
        float sx = sigm(v0.x);
        float sy = sigm(v0.y);
        float cx = (sx + off[2 * ln + 0]) * st[0];
        float cy = (sy + off[2 * ln + 1]) * st[1];
        float hx = 0.5f * expf(v0.z) * anc[2 * ln + 0];
        float hy = 0.5f * expf(v0.w) * anc[2 * ln + 1];
        float4 bb = make_float4(cx - hx, cy - hy, cx + hx, cy + hy);

        size_t base = (size_t)b * MROWS + (size_t)n * C_;
        float* ids = out;
        float* scs = out + (size_t)BATCH_ * MROWS;
        float* bbs = out + 2ull * BATCH_ * MROWS;

        // -1 defaults: never re-read on device -> NT; bbox re-read by topk -> normal
        __builtin_nontemporal_store(-1.0f, &ids[base + 0]);
        __builtin_nontemporal_store(-1.0f, &ids[base + 1]);
        __builtin_nontemporal_store(-1.0f, &ids[base + 2]);
        __builtin_nontemporal_store(-1.0f, &scs[base + 0]);
        __builtin_nontemporal_store(-1.0f, &scs[base + 1]);
        __builtin_nontemporal_store(-1.0f, &scs[base + 2]);
        float4* bp = (float4*)(bbs + base * 4);
        bp[0] = bb; bp[1] = bb; bp[2] = bb;

        // prefilter into LDS staging (LDS atomics only; ~60 positives per block)
        if (listcap > 0) {
            float sobj = sigm(v1.x);
            float s[3] = { sobj * sigm(v1.y), sobj * sigm(v1.z), sobj * sigm(v1.w) };
            #pragma unroll
            for (int c = 0; c < C_; ++c) {
                if (s[c] > TPRE) {
                    unsigned p = atomicAdd(&lcnt[c], 1u);
                    stage[c][p] =
                        ((unsigned long long)__float_as_uint(s[c]) << 32) | (unsigned)(~n);
                }
            }
        }
    }

    if (listcap > 0) {
        __syncthreads();
        // one global atomic per (block, class); counters 128B apart
        if (tid < C_)
            lbase[tid] = atomicAdd(&cnts[(b * C_ + tid) * CNT_STRIDE], lcnt[tid]);
        __syncthreads();
        #pragma unroll
        for (int c = 0; c < C_; ++c) {
            unsigned m = lcnt[c];
            if ((unsigned)tid < m) {
                unsigned pos = lbase[c] + (unsigned)tid;
                if (pos < (unsigned)listcap)
                    list[(size_t)(b * C_ + c) * listcap + pos] = stage[c][tid];
            }
        }
    }
}

// ---------------- kernel 2: per-(b,c) exact top-500 via rank-count sort -> ws ----------------
__global__ __launch_bounds__(512) void topk_kernel(
    const float* __restrict__ o1, const float* __restrict__ o2, const float* __restrict__ o3,
    const float* __restrict__ out,
    const unsigned* __restrict__ cnts, const unsigned long long* __restrict__ list,
    unsigned long long* __restrict__ gkeys, float4* __restrict__ gboxes,
    unsigned* __restrict__ kcnt)
{
    const int g = blockIdx.x;
    const int b = g / C_;
    const int c = g - b * C_;
    const int tid = threadIdx.x;

    // keys[2048] (16KB) + hist[2304]u32 (9.2KB, aliased by skeys[512]u64 after scan)
    __shared__ unsigned long long smem[CCAP + 1152];
    unsigned long long* keys = smem;
    unsigned* hist = (unsigned*)(smem + CCAP);
    unsigned long long* skeys = smem + CCAP;             // alias; hist dead after collect
    __shared__ unsigned int sh_tb, sh_cnt;

    unsigned cnt_g = cnts[g * CNT_STRIDE];
    const bool pathL = (cnt_g >= TOPK && cnt_g <= (unsigned)LISTCAP);
    const unsigned long long* L = list + (size_t)g * LISTCAP;

    // ---- phase 1: histogram of score bit-patterns ----
    for (int i = tid; i < NBINS; i += 512) hist[i] = 0u;
    if (tid == 0) sh_cnt = 0u;
    __syncthreads();

    if (pathL) {
        #pragma unroll 4
        for (unsigned i = tid; i < cnt_g; i += 512) {
            unsigned bin = ((unsigned)(L[i] >> 32) - BASEBITS) >> 14;
            if (bin > NBINS - 1u) bin = NBINS - 1u;
            atomicAdd(&hist[bin], 1u);
        }
    } else {
        for (int n = tid; n < NTOT; n += 512) {
            float s = score_of(b, n, c, o1, o2, o3);
            if (s > 0.05f) {
                unsigned bin = (__float_as_uint(s) - BASEBITS) >> 14;
                if (bin > NBINS - 1u) bin = NBINS - 1u;
                atomicAdd(&hist[bin], 1u);
            }
        }
    }
    __syncthreads();

    // ---- phase 2: wave-0 suffix scan -> threshold bin of the 500th score ----
    scan_tb(hist, &sh_tb);
    __syncthreads();

    // ---- phase 3: collect candidates with bin >= tb (wave-aggregated push) ----
    const unsigned tb = sh_tb;
    if (pathL) {
        unsigned nIter = (cnt_g + 511u) & ~511u;
        #pragma unroll 4
        for (unsigned i = tid; i < nIter; i += 512) {
            bool pred = false; unsigned long long key = 0ull;
            if (i < cnt_g) {
                key = L[i];
                unsigned bin = ((unsigned)(key >> 32) - BASEBITS) >> 14;
                if (bin > NBINS - 1u) bin = NBINS - 1u;
                pred = (bin >= tb);
            }
            unsigned p = wave_push(pred, &sh_cnt);
            if (pred && p < CCAP) keys[p] = key;
        }
    } else {
        const int nIter = (NTOT + 511) & ~511;
        for (int n = tid; n < nIter; n += 512) {
            bool pred = false; unsigned long long key = 0ull;
            if (n < NTOT) {
                float s = score_of(b, n, c, o1, o2, o3);
                if (s > 0.05f) {
                    unsigned bits = __float_as_uint(s);
                    unsigned bin = (bits - BASEBITS) >> 14;
                    if (bin > NBINS - 1u) bin = NBINS - 1u;
                    if (bin >= tb) {
                        pred = true;
                        key = ((unsigned long long)bits << 32) | (unsigned)(~n);
                    }
                }
            }
            unsigned p = wave_push(pred, &sh_cnt);
            if (pred && p < CCAP) keys[p] = key;
        }
    }
    __syncthreads();

    const unsigned cnt2 = min(sh_cnt, (unsigned)CCAP);
    const int K = (int)min(cnt2, (unsigned)TOPK);

    // ---- phase 4: rank-count sort (keys unique; rank = #{key_j > key_m}) ----
    // Inner loop is wave-uniform -> LDS broadcast reads; 3 barriers total vs
    // bitonic's 45 barrier-separated steps (the old stall source).
    for (unsigned m = tid; m < cnt2; m += 512) {
        unsigned long long km = keys[m];
        unsigned rank = 0;
        #pragma unroll 4
        for (unsigned j = 0; j < cnt2; ++j)
            rank += (keys[j] > km) ? 1u : 0u;
        if (rank < 512u) skeys[rank] = km;               // only top-512 ranks kept
    }
    __syncthreads();

    // ---- phase 5: emit sorted keys + gathered boxes to ws ----
    if (tid == 0) kcnt[g] = (unsigned)K;
    if (tid < K) {
        unsigned long long key = skeys[tid];
        gkeys[(size_t)g * 512 + tid] = key;
        unsigned idx = ~(unsigned)(key & 0xFFFFFFFFull);
        const float* bbs = out + 2ull * BATCH_ * MROWS;
        gboxes[(size_t)g * 512 + tid] =
            *(const float4*)(bbs + ((size_t)b * MROWS + (size_t)idx * C_) * 4);
    }
}

// ---------------- kernel 3: mask word-columns; block = (group, word) ----------------
__global__ __launch_bounds__(256) void masks_kernel(
    const float4* __restrict__ gboxes, const unsigned* __restrict__ kcnt,
    unsigned long long* __restrict__ gmasks)
{
    const int g = blockIdx.x;
    const int w = blockIdx.y;
    const int K = (int)kcnt[g];

    __shared__ float bx[TOPK * 4];   // 8 KB
    __shared__ float ar[TOPK];       // 2 KB

    const float4* B = gboxes + (size_t)g * 512;
    for (int j = threadIdx.x; j < K; j += 256) {
        float4 v = B[j];
        bx[j*4+0] = v.x; bx[j*4+1] = v.y; bx[j*4+2] = v.z; bx[j*4+3] = v.w;
        ar[j] = fmaxf(v.z - v.x, 0.0f) * fmaxf(v.w - v.y, 0.0f);
    }
    __syncthreads();

    unsigned long long* M = gmasks + (size_t)g * 4096 + (size_t)w * 512;
    const int j0 = w * 64;
    const int jhi = (K < j0 + 64) ? K : j0 + 64;

    for (int i = threadIdx.x; i < K; i += 256) {
        unsigned long long word = 0ull;
        if (i + 1 < jhi) {
            float xi1 = bx[i*4+0], yi1 = bx[i*4+1], xi2 = bx[i*4+2], yi2 = bx[i*4+3];
            float ai = ar[i];
            // wave-uniform j (broadcast LDS reads); j>i folded into bit test
            for (int j = j0; j < jhi; ++j) {
                float xj1 = bx[j*4+0], yj1 = bx[j*4+1], xj2 = bx[j*4+2], yj2 = bx[j*4+3];
                float aj = ar[j];
                float iw = fmaxf(fminf(xi2, xj2) - fmaxf(xi1, xj1), 0.0f);
                float ih = fmaxf(fminf(yi2, yj2) - fmaxf(yi1, yj1), 0.0f);
                float inter = iw * ih;
                float iou = inter / (ai + aj - inter + 1e-12f);
                if (iou > 0.5f && j > i) word |= 1ull << (j - j0);
            }
        }
        M[i] = word;
    }
}

// ---------------- kernel 4: greedy scan + scatter; block = group ----------------
// Named scalar registers (no arrays -> no spill/remat), branchless vote body.
__global__ __launch_bounds__(512) void greedy_kernel(
    const unsigned long long* __restrict__ gmasks,
    const unsigned long long* __restrict__ gkeys,
    const unsigned* __restrict__ kcnt, float* __restrict__ out)
{
    const int g = blockIdx.x;
    const int b = g / C_;
    const int c = g - b * C_;
    const int tid = threadIdx.x;
    const int K = (int)kcnt[g];

    __shared__ unsigned long long mlds[512 * 9];        // row pad 8->9: conflict-free
    __shared__ unsigned long long keep_s[8];

    // preload masks: coalesced over i for each word w; rows >= K zeroed
    const unsigned long long* GM = gmasks + (size_t)g * 4096;
    for (int t = tid; t < 8 * 512; t += 512) {
        int w = t >> 9, i = t & 511;
        mlds[i * 9 + w] = (i < K) ? GM[w * 512 + i] : 0ull;
    }
    __syncthreads();

    if (tid < 64) {
        const int lane8 = tid & 7;                      // all lanes read word lane8 (broadcast)
        unsigned long long removed = 0ull, keep = 0ull;
        const int Kpad = (K + 7) & ~7;

        unsigned long long m0 = mlds[0*9+lane8], m1 = mlds[1*9+lane8],
                           m2 = mlds[2*9+lane8], m3 = mlds[3*9+lane8],
                           m4 = mlds[4*9+lane8], m5 = mlds[5*9+lane8],
                           m6 = mlds[6*9+lane8], m7 = mlds[7*9+lane8];

        for (int i0 = 0; i0 < Kpad; i0 += 8) {
            int nb = (i0 + 8 < 512) ? (i0 + 8) : 0;     // wrap-safe; values unused at end
            unsigned long long n0 = mlds[(nb+0)*9+lane8], n1 = mlds[(nb+1)*9+lane8],
                               n2 = mlds[(nb+2)*9+lane8], n3 = mlds[(nb+3)*9+lane8],
                               n4 = mlds[(nb+4)*9+lane8], n5 = mlds[(nb+5)*9+lane8],
                               n6 = mlds[(nb+6)*9+lane8], n7 = mlds[(nb+7)*9+lane8];

            #define GSTEP(t, mt) { \
                int i = i0 + t; \
                int w = i >> 6, bp = i & 63; \
                bool mine = (tid == w) && ((removed >> bp) & 1ull); \
                unsigned long long alive = __any(mine) ? 0ull : ~0ull; \
                keep |= ((tid == w) ? (1ull << bp) : 0ull) & alive; \
                removed |= mt & alive; \
            }
            GSTEP(0, m0) GSTEP(1, m1) GSTEP(2, m2) GSTEP(3, m3)
            GSTEP(4, m4) GSTEP(5, m5) GSTEP(6, m6) GSTEP(7, m7)
            #undef GSTEP

            m0=n0; m1=n1; m2=n2; m3=n3; m4=n4; m5=n5; m6=n6; m7=n7;
        }
        if (tid < 8) keep_s[tid] = keep;
    }
    __syncthreads();

    const unsigned long long* GK = gkeys + (size_t)g * 512;
    for (int i = tid; i < K; i += 512) {
        if ((keep_s[i >> 6] >> (i & 63)) & 1ull) {
            unsigned long long key = GK[i];
            unsigned idx = ~(unsigned)(key & 0xFFFFFFFFull);
            float sc = __uint_as_float((unsigned)(key >> 32));
            size_t row = (size_t)b * MROWS + (size_t)idx * C_ + c;
            out[row] = (float)c;                               // id
            out[(size_t)BATCH_ * MROWS + row] = sc;            // score
        }
    }
}

// ---------------- monolithic fallback (small ws; full in-kernel rescan) ----------------
__global__ __launch_bounds__(512) void select_nms_mono(
    const float* __restrict__ o1, const float* __restrict__ o2, const float* __restrict__ o3,
    float* __restrict__ out)
{
    const int g = blockIdx.x;
    const int b = g / C_;
    const int c = g - b * C_;
    const int tid = threadIdx.x;

    __shared__ unsigned long long smem[7048];
    __shared__ unsigned int sh_tb, sh_cnt;
    __shared__ unsigned long long keepw[8];

    unsigned long long* keys = smem;
    unsigned* hist = (unsigned*)(smem + CCAP);
    unsigned long long* skeys = smem + CCAP;             // alias over hist
    float* boxes = (float*)(smem + CCAP + 600);
    unsigned long long* masks = smem + 3048;

    for (int i = tid; i < NBINS; i += 512) hist[i] = 0u;
    if (tid == 0) sh_cnt = 0u;
    __syncthreads();

    for (int n = tid; n < NTOT; n += 512) {
        float s = score_of(b, n, c, o1, o2, o3);
        if (s > 0.05f) {
            unsigned bin = (__float_as_uint(s) - BASEBITS) >> 14;
            if (bin > NBINS - 1u) bin = NBINS - 1u;
            atomicAdd(&hist[bin], 1u);
        }
    }
    __syncthreads();
    scan_tb(hist, &sh_tb);
    __syncthreads();

    const unsigned tb = sh_tb;
    for (int n = tid; n < NTOT; n += 512) {
        float s = score_of(b, n, c, o1, o2, o3);
        if (s > 0.05f) {
            unsigned bits = __float_as_uint(s);
            unsigned bin = (bits - BASEBITS) >> 14;
            if (bin > NBINS - 1u) bin = NBINS - 1u;
            if (bin >= tb) {
                unsigned p = atomicAdd(&sh_cnt, 1u);
                if (p < CCAP)
                    keys[p] = ((unsigned long long)bits << 32) | (unsigned)(~n);
            }
        }
    }
    __syncthreads();

    const unsigned cnt2 = min(sh_cnt, (unsigned)CCAP);
    const int K = (int)min(cnt2, (unsigned)TOPK);

    // rank-count sort into skeys (hist region dead)
    for (unsigned m = tid; m < cnt2; m += 512) {
        unsigned long long km = keys[m];
        unsigned rank = 0;
        for (unsigned j = 0; j < cnt2; ++j)
            rank += (keys[j] > km) ? 1u : 0u;
        if (rank < 512u) skeys[rank] = km;
    }
    __syncthreads();
    // move top-K back to keys[0..K) (stable region for scatter phase)
    if (tid < K) keys[tid] = skeys[tid];
    __syncthreads();

    {
        const float* bbs = out + 2ull * BATCH_ * MROWS;
        if (tid < K) {
            unsigned idx = ~(unsigned)(keys[tid] & 0xFFFFFFFFull);
            float4 bb = *(const float4*)(bbs + ((size_t)b * MROWS + (size_t)idx * C_) * 4);
            ((float4*)boxes)[tid] = bb;
        }
    }
    __syncthreads();

    {
        const int nw = (K + 63) >> 6;
        for (int t = tid; t < K * nw; t += 512) {
            int w = t / K;
            int i = t - w * K;
            float xi1 = boxes[i*4+0], yi1 = boxes[i*4+1], xi2 = boxes[i*4+2], yi2 = boxes[i*4+3];
            float ai = fmaxf(xi2 - xi1, 0.0f) * fmaxf(yi2 - yi1, 0.0f);
            unsigned long long word = 0ull;
            int jlo = (i + 1 > w * 64) ? i + 1 : w * 64;
            int jhi = (K < (w + 1) * 64) ? K : (w + 1) * 64;
            for (int j = jlo; j < jhi; ++j) {
                float xj1 = boxes[j*4+0], yj1 = boxes[j*4+1], xj2 = boxes[j*4+2], yj2 = boxes[j*4+3];
                float aj = fmaxf(xj2 - xj1, 0.0f) * fmaxf(yj2 - yj1, 0.0f);
                float iw = fmaxf(fminf(xi2, xj2) - fmaxf(xi1, xj1), 0.0f);
                float ih = fmaxf(fminf(yi2, yj2) - fmaxf(yi1, yj1), 0.0f);
                float inter = iw * ih;
                float iou = inter / (ai + aj - inter + 1e-12f);
                if (iou > 0.5f) word |= 1ull << (j & 63);
            }
            masks[i * 8 + w] = word;
        }
    }
    __syncthreads();

    if (tid < 64) {
        unsigned long long removed = 0ull, keep = 0ull;
        for (int i = 0; i < K; ++i) {
            unsigned long long mw = (tid < 8) ? masks[i * 8 + tid] : 0ull;
            int w = i >> 6, bp = i & 63;
            bool mine = (tid == w) && ((removed >> bp) & 1ull);
            if (!__any(mine)) {
                if (tid == w) keep |= 1ull << bp;
                removed |= mw;
            }
        }
        if (tid < 8) keepw[tid] = keep;
    }
    __syncthreads();

    if (tid < K && ((keepw[tid >> 6] >> (tid & 63)) & 1ull)) {
        unsigned long long key = keys[tid];
        unsigned idx = ~(unsigned)(key & 0xFFFFFFFFull);
        float sc = __uint_as_float((unsigned)(key >> 32));
        size_t row = (size_t)b * MROWS + (size_t)idx * C_ + c;
        out[row] = (float)c;
        out[(size_t)BATCH_ * MROWS + row] = sc;
    }
}

extern "C" void kernel_launch(void* const* d_in, const int* in_sizes, int n_in,
                              void* d_out, int out_size, void* d_ws, size_t ws_size,
                              hipStream_t stream)
{
    const float* o1 = (const float*)d_in[0];
    const float* o2 = (const float*)d_in[1];
    const float* o3 = (const float*)d_in[2];
    const float* a1 = (const float*)d_in[3];
    const float* a2 = (const float*)d_in[4];
    const float* a3 = (const float*)d_in[5];
    const float* f1 = (const float*)d_in[6];
    const float* f2 = (const float*)d_in[7];
    const float* f3 = (const float*)d_in[8];
    const float* s1 = (const float*)d_in[9];
    const float* s2 = (const float*)d_in[10];
    const float* s3 = (const float*)d_in[11];
    float* out = (float*)d_out;

    unsigned* cnts = (unsigned*)d_ws;

    if (ws_size >= WS_NEED) {
        unsigned long long* list   = (unsigned long long*)((char*)d_ws + OFF_LIST);
        unsigned long long* gkeys  = (unsigned long long*)((char*)d_ws + OFF_KEYS);
        float4*             gboxes = (float4*)((char*)d_ws + OFF_BOXES);
        unsigned long long* gmasks = (unsigned long long*)((char*)d_ws + OFF_MASKS);
        unsigned*           kcnt   = (unsigned*)((char*)d_ws + OFF_KCNT);

        zerocnt_kernel<<<dim3(1), dim3(64), 0, stream>>>(cnts);
        decode_filter_kernel<<<dim3((NTOT + 255) / 256, BATCH_), dim3(256), 0, stream>>>(
            o1, o2, o3, a1, a2, a3, f1, f2, f3, s1, s2, s3, out, cnts, list, LISTCAP);
        topk_kernel<<<dim3(GRP), dim3(512), 0, stream>>>(
            o1, o2, o3, out, cnts, list, gkeys, gboxes, kcnt);
        masks_kernel<<<dim3(GRP, 8), dim3(256), 0, stream>>>(gboxes, kcnt, gmasks);
        greedy_kernel<<<dim3(GRP), dim3(512), 0, stream>>>(gmasks, gkeys, kcnt, out);
    } else {
        decode_filter_kernel<<<dim3((NTOT + 255) / 256, BATCH_), dim3(256), 0, stream>>>(
            o1, o2, o3, a1, a2, a3, f1, f2, f3, s1, s2, s3, out, nullptr, nullptr, 0);
        select_nms_mono<<<dim3(GRP), dim3(512), 0, stream>>>(o1, o2, o3, out);
    }
}